// Round 11
// baseline (666.866 us; speedup 1.0000x reference)
//
#include <hip/hip_runtime.h>
#include <hip/hip_bf16.h>
#include <hip/hip_fp16.h>

#define N_NODES 50000
#define F_IN    64
#define HDIM    256
#define E_EDGES 800000
#define G_GRAPHS 2048
#define L_LAYERS 4
#define T_OUT   4
#define BN_EPS  1e-5f

#define NPAD    50176   // 196 * 256
#define NBLK    196
#define LDK     264     // fp16 LDS row stride for K=256 tiles

// Wt buffer offsets (fp16 elements)
#define WT_CONV 0
#define WT_PROJ 262144
#define WT_H1   278528
#define WT_H2   409600
#define WT_TOT  442368

typedef _Float16 half8 __attribute__((ext_vector_type(8)));
typedef float    f32x4 __attribute__((ext_vector_type(4)));

// ---- degree count + all weight transposes (fused, independent work) --------
__global__ void k_deg_wcvt(const int* __restrict__ dst, int* __restrict__ cnt,
                           const float* __restrict__ convW, const float* __restrict__ projW,
                           const float* __restrict__ W1, const float* __restrict__ W2,
                           _Float16* __restrict__ Wt) {
    int i = blockIdx.x * 256 + threadIdx.x;
    if (i < E_EDGES) atomicAdd(&cnt[dst[i]], 1);
    if (i < 262144) {                       // conv: 4 x [256x256]
        int l = i >> 16, r = i & 65535;
        int k = r >> 8, n = r & 255;
        Wt[WT_CONV + (size_t)l * 65536 + n * 256 + k] = (_Float16)convW[(size_t)l * 65536 + k * 256 + n];
        return;
    }
    int j = i - 262144;
    if (j >= 0 && j < 16384) {              // proj: [64x256] -> [256][64]
        int k = j >> 8, n = j & 255;
        Wt[WT_PROJ + n * 64 + k] = (_Float16)projW[k * 256 + n];
        return;
    }
    j -= 16384;
    if (j >= 0 && j < 131072) {             // W1: [512x256] -> [256][512]
        int k = j >> 8, n = j & 255;
        Wt[WT_H1 + n * 512 + k] = (_Float16)W1[k * 256 + n];
        return;
    }
    j -= 131072;
    if (j >= 0 && j < 32768) {              // W2: [256x128] -> [128][256]
        int k = j >> 7, n = j & 127;
        Wt[WT_H2 + n * 256 + k] = (_Float16)W2[k * 128 + n];
    }
}

// ---- scan pass 1: per-block inclusive scan ---------------------------------
__global__ void k_scan1(const int* __restrict__ cnt, int* __restrict__ iscan,
                        int* __restrict__ bsum) {
    __shared__ int sm[256];
    int t = threadIdx.x, i = blockIdx.x * 256 + t;
    sm[t] = cnt[i];
    __syncthreads();
    for (int off = 1; off < 256; off <<= 1) {
        int u = (t >= off) ? sm[t - off] : 0;
        __syncthreads();
        sm[t] += u;
        __syncthreads();
    }
    iscan[i] = sm[t];
    if (t == 255) bsum[blockIdx.x] = sm[255];
}

// ---- scan pass 2: block offset computed locally + emit rowptr/wpos/inv -----
__global__ void k_scan23(const int* __restrict__ cnt, const int* __restrict__ iscan,
                         const int* __restrict__ bsum, int* __restrict__ rowptr,
                         int* __restrict__ wpos, float* __restrict__ inv) {
    __shared__ int sm[256];
    int t = threadIdx.x;
    int b = blockIdx.x;
    sm[t] = (t < b) ? bsum[t] : 0;   // t < b <= 195 < NBLK
    __syncthreads();
    for (int off = 128; off > 0; off >>= 1) {
        if (t < off) sm[t] += sm[t + off];
        __syncthreads();
    }
    int boff = sm[0];
    int i = b * 256 + t;
    int c = cnt[i];
    int excl = boff + iscan[i] - c;
    rowptr[i] = excl;
    wpos[i] = excl;
    inv[i] = rsqrtf((float)c + 1.0f);
}

// ---- scatter edges into CSR order (src ids fit in ushort: N < 65536) -------
__global__ void k_scatter(const int* __restrict__ ei, int* __restrict__ wpos,
                          ushort* __restrict__ csr_src) {
    int e = blockIdx.x * blockDim.x + threadIdx.x;
    if (e < E_EDGES) {
        int s = ei[e];
        int d = ei[E_EDGES + e];
        int pos = atomicAdd(&wpos[d], 1);
        csr_src[pos] = (ushort)s;
    }
}

// ---- proj GEMM via MFMA: h16 = fp16(relu(x @ Wp + b)) ----------------------
__global__ __launch_bounds__(256) void k_proj_mfma(const float* __restrict__ x,
                                                   const _Float16* __restrict__ Wpt,
                                                   const float* __restrict__ bias,
                                                   ushort* __restrict__ h16, int nrows) {
    __shared__ _Float16 hs[64 * 72];
    int block_r = blockIdx.x * 64;
    for (int i = threadIdx.x; i < 64 * 16; i += 256) {
        int row = i >> 4;
        int c4 = (i & 15) * 4;
        float4 v = (block_r + row < nrows)
                       ? *(const float4*)(x + (size_t)(block_r + row) * F_IN + c4)
                       : make_float4(0.f, 0.f, 0.f, 0.f);
        _Float16* p = &hs[row * 72 + c4];
        p[0] = (_Float16)v.x; p[1] = (_Float16)v.y;
        p[2] = (_Float16)v.z; p[3] = (_Float16)v.w;
    }
    __syncthreads();

    int wave = threadIdx.x >> 6;
    int lane = threadIdx.x & 63;
    int l16 = lane & 15;
    int quad = lane >> 4;
    int n0 = wave * 64;

    f32x4 acc[4][4] = {};
#pragma unroll
    for (int k0 = 0; k0 < F_IN; k0 += 32) {
        half8 a[4], b[4];
#pragma unroll
        for (int ai = 0; ai < 4; ai++)
            a[ai] = *(const half8*)&hs[(ai * 16 + l16) * 72 + k0 + quad * 8];
#pragma unroll
        for (int bj = 0; bj < 4; bj++)
            b[bj] = *(const half8*)&Wpt[(size_t)(n0 + bj * 16 + l16) * F_IN + k0 + quad * 8];
#pragma unroll
        for (int ai = 0; ai < 4; ai++)
#pragma unroll
            for (int bj = 0; bj < 4; bj++)
                acc[ai][bj] = __builtin_amdgcn_mfma_f32_16x16x32_f16(a[ai], b[bj], acc[ai][bj], 0, 0, 0);
    }

#pragma unroll
    for (int ai = 0; ai < 4; ai++) {
        int rowb = block_r + ai * 16 + quad * 4;
#pragma unroll
        for (int r = 0; r < 4; r++) {
            int row = rowb + r;
            if (row >= nrows) continue;
#pragma unroll
            for (int bj = 0; bj < 4; bj++) {
                int col = n0 + bj * 16 + l16;
                float v = fmaxf(acc[ai][bj][r] + bias[col], 0.f);
                h16[(size_t)row * HDIM + col] = __half_as_ushort(__float2half(v));
            }
        }
    }
}

// ---- conv GEMM via MFMA: hWh = fp16((h16 @ W) * inv[row]) ------------------
__global__ __launch_bounds__(256) void k_gemm_mfma(const ushort* __restrict__ h16,
                                                   const _Float16* __restrict__ Wt,
                                                   const float* __restrict__ inv,
                                                   _Float16* __restrict__ outh, int nrows) {
    __shared__ _Float16 hs[64 * LDK];
    int block_r = blockIdx.x * 64;
    for (int i = threadIdx.x; i < 64 * 32; i += 256) {
        int row = i >> 5;
        int c16 = (i & 31) * 8;
        uint4 v;
        if (block_r + row < nrows)
            v = *(const uint4*)(h16 + (size_t)(block_r + row) * HDIM + c16);
        else
            v = make_uint4(0u, 0u, 0u, 0u);
        *(uint4*)&hs[row * LDK + c16] = v;
    }
    __syncthreads();

    int wave = threadIdx.x >> 6;
    int lane = threadIdx.x & 63;
    int l16 = lane & 15;
    int quad = lane >> 4;
    int n0 = wave * 64;

    f32x4 acc[4][4] = {};
    for (int k0 = 0; k0 < HDIM; k0 += 32) {
        half8 a[4], b[4];
#pragma unroll
        for (int ai = 0; ai < 4; ai++)
            a[ai] = *(const half8*)&hs[(ai * 16 + l16) * LDK + k0 + quad * 8];
#pragma unroll
        for (int bj = 0; bj < 4; bj++)
            b[bj] = *(const half8*)&Wt[(size_t)(n0 + bj * 16 + l16) * HDIM + k0 + quad * 8];
#pragma unroll
        for (int ai = 0; ai < 4; ai++)
#pragma unroll
            for (int bj = 0; bj < 4; bj++)
                acc[ai][bj] = __builtin_amdgcn_mfma_f32_16x16x32_f16(a[ai], b[bj], acc[ai][bj], 0, 0, 0);
    }

#pragma unroll
    for (int ai = 0; ai < 4; ai++) {
        int rowb = block_r + ai * 16 + quad * 4;
#pragma unroll
        for (int r = 0; r < 4; r++) {
            int row = rowb + r;
            if (row >= nrows) continue;
            float sc = inv[row];
#pragma unroll
            for (int bj = 0; bj < 4; bj++) {
                outh[(size_t)row * HDIM + n0 + bj * 16 + l16] = (_Float16)(acc[ai][bj][r] * sc);
            }
        }
    }
}

// ---- fused CSR aggregation + self-loop + bias + BN + relu + residual -------
// fp16 packed accumulate, 8 outstanding uint4 gathers. (R10 version, at its
// pattern ceiling: FETCH = per-XCD compulsory floor, ~3.7 TB/s random rows.)
__global__ __launch_bounds__(256) void k_aggr(const int* __restrict__ rowptr,
                                              const ushort* __restrict__ csr,
                                              const ushort* __restrict__ hWh,
                                              const float* __restrict__ inv,
                                              const float* __restrict__ cb,
                                              const float* __restrict__ gamma,
                                              const float* __restrict__ beta,
                                              const float* __restrict__ mean,
                                              const float* __restrict__ var,
                                              ushort* __restrict__ h16) {
    int node = blockIdx.x * 4 + (threadIdx.x >> 6);
    if (node >= N_NODES) return;
    int lane = threadIdx.x & 63;
    int g = lane >> 5;     // edge sub-slot (0/1)
    int f = lane & 31;     // 16B granule: features f*8 .. f*8+7
    const uint4* tbl = (const uint4*)hWh;   // row = 32 granules

    __half2 acc4[4];
#pragma unroll
    for (int i = 0; i < 4; i++) acc4[i] = __floats2half2_rn(0.f, 0.f);

    int beg = rowptr[node], end = rowptr[node + 1];
    for (int base = beg; base < end; base += 64) {
        int m = end - base; if (m > 64) m = 64;
        int myidx = (lane < m) ? (int)csr[base + lane] : 0;
        int jj = 0;
        for (; jj + 16 <= m; jj += 16) {
            int s0 = __shfl(myidx, jj + 0 + g);
            int s1 = __shfl(myidx, jj + 2 + g);
            int s2 = __shfl(myidx, jj + 4 + g);
            int s3 = __shfl(myidx, jj + 6 + g);
            int s4 = __shfl(myidx, jj + 8 + g);
            int s5 = __shfl(myidx, jj + 10 + g);
            int s6 = __shfl(myidx, jj + 12 + g);
            int s7 = __shfl(myidx, jj + 14 + g);
            uint4 u0 = tbl[(size_t)s0 * 32 + f];
            uint4 u1 = tbl[(size_t)s1 * 32 + f];
            uint4 u2 = tbl[(size_t)s2 * 32 + f];
            uint4 u3 = tbl[(size_t)s3 * 32 + f];
            uint4 u4 = tbl[(size_t)s4 * 32 + f];
            uint4 u5 = tbl[(size_t)s5 * 32 + f];
            uint4 u6 = tbl[(size_t)s6 * 32 + f];
            uint4 u7 = tbl[(size_t)s7 * 32 + f];
            const __half2* p0 = (const __half2*)&u0;
            const __half2* p1 = (const __half2*)&u1;
            const __half2* p2 = (const __half2*)&u2;
            const __half2* p3 = (const __half2*)&u3;
            const __half2* p4 = (const __half2*)&u4;
            const __half2* p5 = (const __half2*)&u5;
            const __half2* p6 = (const __half2*)&u6;
            const __half2* p7 = (const __half2*)&u7;
#pragma unroll
            for (int i = 0; i < 4; i++) {
                __half2 a = __hadd2(__hadd2(p0[i], p1[i]), __hadd2(p2[i], p3[i]));
                __half2 b = __hadd2(__hadd2(p4[i], p5[i]), __hadd2(p6[i], p7[i]));
                acc4[i] = __hadd2(acc4[i], __hadd2(a, b));
            }
        }
        if (jj + 8 <= m) {
            int s0 = __shfl(myidx, jj + 0 + g);
            int s1 = __shfl(myidx, jj + 2 + g);
            int s2 = __shfl(myidx, jj + 4 + g);
            int s3 = __shfl(myidx, jj + 6 + g);
            uint4 u0 = tbl[(size_t)s0 * 32 + f];
            uint4 u1 = tbl[(size_t)s1 * 32 + f];
            uint4 u2 = tbl[(size_t)s2 * 32 + f];
            uint4 u3 = tbl[(size_t)s3 * 32 + f];
            const __half2* p0 = (const __half2*)&u0;
            const __half2* p1 = (const __half2*)&u1;
            const __half2* p2 = (const __half2*)&u2;
            const __half2* p3 = (const __half2*)&u3;
#pragma unroll
            for (int i = 0; i < 4; i++)
                acc4[i] = __hadd2(acc4[i], __hadd2(__hadd2(p0[i], p1[i]), __hadd2(p2[i], p3[i])));
            jj += 8;
        }
        for (; jj < m; jj += 2) {
            int e = jj + g;
            int s = __shfl(myidx, (e < m) ? e : (m - 1));
            uint4 u = tbl[(size_t)s * 32 + f];
            if (e < m) {
                const __half2* p = (const __half2*)&u;
#pragma unroll
                for (int i = 0; i < 4; i++) acc4[i] = __hadd2(acc4[i], p[i]);
            }
        }
    }

#pragma unroll
    for (int i = 0; i < 4; i++) {
        unsigned int packed = *(unsigned int*)&acc4[i];
        unsigned int other = __shfl_xor((int)packed, 32);
        acc4[i] = __hadd2(acc4[i], *(__half2*)&other);
    }

    if (g == 0) {
        float acc[8];
#pragma unroll
        for (int i = 0; i < 4; i++) {
            float2 t = __half22float2(acc4[i]);
            acc[2 * i] = t.x; acc[2 * i + 1] = t.y;
        }
        uint4 us = tbl[(size_t)node * 32 + f];
        const __half2* ps = (const __half2*)&us;
#pragma unroll
        for (int i = 0; i < 4; i++) {
            float2 t = __half22float2(ps[i]);
            acc[2 * i] += t.x;
            acc[2 * i + 1] += t.y;
        }
        int c0 = f * 8;
        float iv = inv[node];
        uint4 ur = *(const uint4*)(h16 + (size_t)node * HDIM + c0);
        const __half2* pr = (const __half2*)&ur;
        float resv[8];
#pragma unroll
        for (int i = 0; i < 4; i++) {
            float2 rr = __half22float2(pr[i]);
            resv[2 * i] = rr.x; resv[2 * i + 1] = rr.y;
        }
        float r8[8];
#pragma unroll
        for (int half = 0; half < 2; half++) {
            int c = c0 + half * 4;
            float4 bb = *(const float4*)(cb + c);
            float4 gm = *(const float4*)(gamma + c);
            float4 bt = *(const float4*)(beta + c);
            float4 mn = *(const float4*)(mean + c);
            float4 vr = *(const float4*)(var + c);
            float* a = &acc[half * 4];
            float* rs = &resv[half * 4];
            r8[half * 4 + 0] = fmaxf((a[0] * iv + bb.x - mn.x) * rsqrtf(vr.x + BN_EPS) * gm.x + bt.x, 0.f) + rs[0];
            r8[half * 4 + 1] = fmaxf((a[1] * iv + bb.y - mn.y) * rsqrtf(vr.y + BN_EPS) * gm.y + bt.y, 0.f) + rs[1];
            r8[half * 4 + 2] = fmaxf((a[2] * iv + bb.z - mn.z) * rsqrtf(vr.z + BN_EPS) * gm.z + bt.z, 0.f) + rs[2];
            r8[half * 4 + 3] = fmaxf((a[3] * iv + bb.w - mn.w) * rsqrtf(vr.w + BN_EPS) * gm.w + bt.w, 0.f) + rs[3];
        }
        __half2 q0 = __floats2half2_rn(r8[0], r8[1]);
        __half2 q1 = __floats2half2_rn(r8[2], r8[3]);
        __half2 q2 = __floats2half2_rn(r8[4], r8[5]);
        __half2 q3 = __floats2half2_rn(r8[6], r8[7]);
        uint4 uo;
        uo.x = *(unsigned int*)&q0; uo.y = *(unsigned int*)&q1;
        uo.z = *(unsigned int*)&q2; uo.w = *(unsigned int*)&q3;
        *(uint4*)(h16 + (size_t)node * HDIM + c0) = uo;
    }
}

// ---- fused pool + head1: block = 64 graphs; gp tile lives in LDS -----------
// Pool: wave w, sub s handle graphs j*8 + w*2 + s; lane granule covers 8 feats.
// Then head1 MFMA (K=512) reads the tile directly (LDKH = 520).
__global__ __launch_bounds__(256) void k_pool_head1(const ushort* __restrict__ h16,
                                                    const int* __restrict__ batch,
                                                    const _Float16* __restrict__ W1t,
                                                    const float* __restrict__ b1,
                                                    ushort* __restrict__ g1h) {
    __shared__ _Float16 hs[64 * 520];
    __shared__ int slo[64], shi[64];
    int g0 = blockIdx.x * 64;
    int t = threadIdx.x;
    if (t < 64) {
        int g = g0 + t;
        int lo = 0, hi = N_NODES;
        while (lo < hi) { int m = (lo + hi) >> 1; if (batch[m] < g) lo = m + 1; else hi = m; }
        slo[t] = lo;
        hi = N_NODES;
        while (lo < hi) { int m = (lo + hi) >> 1; if (batch[m] < g + 1) lo = m + 1; else hi = m; }
        shi[t] = lo;
    }
    __syncthreads();

    int wave = t >> 6;
    int lane = t & 63;
    int sub = lane >> 5;
    int l = lane & 31;
    for (int j = 0; j < 8; j++) {
        int gg = j * 8 + wave * 2 + sub;
        int lo = slo[gg], hi = shi[gg];
        float sum[8], mx[8];
#pragma unroll
        for (int i = 0; i < 8; i++) { sum[i] = 0.f; mx[i] = -1e30f; }
        for (int n = lo; n < hi; n++) {
            uint4 u = *(const uint4*)(h16 + (size_t)n * HDIM + l * 8);
            const __half2* p = (const __half2*)&u;
#pragma unroll
            for (int i = 0; i < 4; i++) {
                float2 v = __half22float2(p[i]);
                sum[2 * i] += v.x; sum[2 * i + 1] += v.y;
                mx[2 * i] = fmaxf(mx[2 * i], v.x);
                mx[2 * i + 1] = fmaxf(mx[2 * i + 1], v.y);
            }
        }
        float cntf = fmaxf((float)(hi - lo), 1.0f);
        bool nz = hi > lo;
        __half2 s0 = __floats2half2_rn(sum[0] / cntf, sum[1] / cntf);
        __half2 s1 = __floats2half2_rn(sum[2] / cntf, sum[3] / cntf);
        __half2 s2 = __floats2half2_rn(sum[4] / cntf, sum[5] / cntf);
        __half2 s3 = __floats2half2_rn(sum[6] / cntf, sum[7] / cntf);
        __half2 m0 = __floats2half2_rn(nz ? mx[0] : 0.f, nz ? mx[1] : 0.f);
        __half2 m1 = __floats2half2_rn(nz ? mx[2] : 0.f, nz ? mx[3] : 0.f);
        __half2 m2 = __floats2half2_rn(nz ? mx[4] : 0.f, nz ? mx[5] : 0.f);
        __half2 m3 = __floats2half2_rn(nz ? mx[6] : 0.f, nz ? mx[7] : 0.f);
        uint4 us, um;
        us.x = *(unsigned int*)&s0; us.y = *(unsigned int*)&s1;
        us.z = *(unsigned int*)&s2; us.w = *(unsigned int*)&s3;
        um.x = *(unsigned int*)&m0; um.y = *(unsigned int*)&m1;
        um.z = *(unsigned int*)&m2; um.w = *(unsigned int*)&m3;
        *(uint4*)&hs[gg * 520 + l * 8] = us;
        *(uint4*)&hs[gg * 520 + 256 + l * 8] = um;
    }
    __syncthreads();

    // head1 MFMA: K=512
    int l16 = lane & 15;
    int quad = lane >> 4;
    int n0 = wave * 64;
    f32x4 acc[4][4] = {};
    for (int k0 = 0; k0 < 512; k0 += 32) {
        half8 a[4], b[4];
#pragma unroll
        for (int ai = 0; ai < 4; ai++)
            a[ai] = *(const half8*)&hs[(ai * 16 + l16) * 520 + k0 + quad * 8];
#pragma unroll
        for (int bj = 0; bj < 4; bj++)
            b[bj] = *(const half8*)&W1t[(size_t)(n0 + bj * 16 + l16) * 512 + k0 + quad * 8];
#pragma unroll
        for (int ai = 0; ai < 4; ai++)
#pragma unroll
            for (int bj = 0; bj < 4; bj++)
                acc[ai][bj] = __builtin_amdgcn_mfma_f32_16x16x32_f16(a[ai], b[bj], acc[ai][bj], 0, 0, 0);
    }
#pragma unroll
    for (int ai = 0; ai < 4; ai++) {
        int rowb = ai * 16 + quad * 4;
#pragma unroll
        for (int r = 0; r < 4; r++) {
            int row = g0 + rowb + r;
#pragma unroll
            for (int bj = 0; bj < 4; bj++) {
                int col = n0 + bj * 16 + l16;
                float v = fmaxf(acc[ai][bj][r] + b1[col], 0.f);
                g1h[(size_t)row * HDIM + col] = __half_as_ushort(__float2half(v));
            }
        }
    }
}

// ---- fused head2 + head3: block = 64 graphs, 128 threads -------------------
__global__ __launch_bounds__(128) void k_head23(const ushort* __restrict__ g1h,
                                                const _Float16* __restrict__ W2t,
                                                const float* __restrict__ b2,
                                                const float* __restrict__ W3,
                                                const float* __restrict__ b3,
                                                float* __restrict__ out) {
    __shared__ _Float16 hs[64 * 264];
    __shared__ float g2s[64 * 132];
    int block_r = blockIdx.x * 64;
    for (int i = threadIdx.x; i < 64 * 32; i += 128) {
        int row = i >> 5;
        int c = (i & 31) * 8;
        *(uint4*)&hs[row * 264 + c] = *(const uint4*)(g1h + (size_t)(block_r + row) * HDIM + c);
    }
    __syncthreads();

    int wave = threadIdx.x >> 6;
    int lane = threadIdx.x & 63;
    int l16 = lane & 15;
    int quad = lane >> 4;
    int n0 = wave * 64;

    f32x4 acc[4][4] = {};
    for (int k0 = 0; k0 < HDIM; k0 += 32) {
        half8 a[4], b[4];
#pragma unroll
        for (int ai = 0; ai < 4; ai++)
            a[ai] = *(const half8*)&hs[(ai * 16 + l16) * 264 + k0 + quad * 8];
#pragma unroll
        for (int bj = 0; bj < 4; bj++)
            b[bj] = *(const half8*)&W2t[(size_t)(n0 + bj * 16 + l16) * HDIM + k0 + quad * 8];
#pragma unroll
        for (int ai = 0; ai < 4; ai++)
#pragma unroll
            for (int bj = 0; bj < 4; bj++)
                acc[ai][bj] = __builtin_amdgcn_mfma_f32_16x16x32_f16(a[ai], b[bj], acc[ai][bj], 0, 0, 0);
    }
#pragma unroll
    for (int ai = 0; ai < 4; ai++) {
        int rowb = ai * 16 + quad * 4;
#pragma unroll
        for (int r = 0; r < 4; r++) {
            int row = rowb + r;
#pragma unroll
            for (int bj = 0; bj < 4; bj++) {
                int col = n0 + bj * 16 + l16;
                g2s[row * 132 + col] = fmaxf(acc[ai][bj][r] + b2[col], 0.f);
            }
        }
    }
    __syncthreads();

    // head3: 64 rows x 4 cols; thread -> (row, col pair)
    int r = threadIdx.x >> 1;
    int p = threadIdx.x & 1;
    float a0 = b3[2 * p], a1 = b3[2 * p + 1];
    for (int k = 0; k < 128; k++) {
        float v = g2s[r * 132 + k];
        a0 += v * W3[k * T_OUT + 2 * p];
        a1 += v * W3[k * T_OUT + 2 * p + 1];
    }
    out[(size_t)(block_r + r) * T_OUT + 2 * p] = a0;
    out[(size_t)(block_r + r) * T_OUT + 2 * p + 1] = a1;
}

extern "C" void kernel_launch(void* const* d_in, const int* in_sizes, int n_in,
                              void* d_out, int out_size, void* d_ws, size_t ws_size,
                              hipStream_t stream) {
    const float* x     = (const float*)d_in[0];
    const int*   ei    = (const int*)d_in[1];
    const int*   batch = (const int*)d_in[2];
    const float* projW = (const float*)d_in[3];
    const float* projb = (const float*)d_in[4];
    const float* convW = (const float*)d_in[5];
    const float* convb = (const float*)d_in[6];
    const float* gamma = (const float*)d_in[7];
    const float* beta  = (const float*)d_in[8];
    const float* mean  = (const float*)d_in[9];
    const float* var   = (const float*)d_in[10];
    const float* W1    = (const float*)d_in[11];
    const float* b1    = (const float*)d_in[12];
    const float* W2    = (const float*)d_in[13];
    const float* b2    = (const float*)d_in[14];
    const float* W3    = (const float*)d_in[15];
    const float* b3    = (const float*)d_in[16];
    float* out = (float*)d_out;

    // workspace layout (all segments 16B aligned)
    float*  wsf    = (float*)d_ws;
    float*  inv    = wsf;                        // NPAD f
    int*    cnt    = (int*)(wsf + NPAD);         // NPAD i
    int*    rowptr = cnt + NPAD;                 // NPAD i
    int*    wpos   = rowptr + NPAD;              // NPAD i
    int*    iscan  = wpos + NPAD;                // NPAD i
    int*    bsum   = iscan + NPAD;               // 256 i
    int*    boff   = bsum + 256;                 // 256 i (unused, kept for layout)
    ushort* csr    = (ushort*)(boff + 256);      // 800256 u16
    ushort* hWh    = csr + 800256;               // N*H fp16 (messages)
    ushort* h16    = hWh + (size_t)N_NODES * HDIM;            // N*H fp16 residual stream
    ushort* g1h    = h16 + (size_t)N_NODES * HDIM;            // G*256 fp16
    _Float16* Wt   = (_Float16*)(g1h + (size_t)G_GRAPHS * HDIM); // WT_TOT fp16

    // ---- CSR build + weight transposes ----
    hipMemsetAsync(cnt, 0, NPAD * sizeof(int), stream);
    k_deg_wcvt<<<(E_EDGES + 255) / 256, 256, 0, stream>>>(ei + E_EDGES, cnt,
                                                          convW, projW, W1, W2, Wt);
    k_scan1<<<NBLK, 256, 0, stream>>>(cnt, iscan, bsum);
    k_scan23<<<NBLK, 256, 0, stream>>>(cnt, iscan, bsum, rowptr, wpos, inv);
    k_scatter<<<(E_EDGES + 255) / 256, 256, 0, stream>>>(ei, wpos, csr);

    // ---- proj (MFMA) ----
    int gemm_blocks = (N_NODES + 63) / 64;
    k_proj_mfma<<<gemm_blocks, 256, 0, stream>>>(x, Wt + WT_PROJ, projb, h16, N_NODES);

    // ---- GCN layers ----
    for (int l = 0; l < L_LAYERS; l++) {
        k_gemm_mfma<<<gemm_blocks, 256, 0, stream>>>(h16, Wt + WT_CONV + (size_t)l * HDIM * HDIM,
                                                     inv, (_Float16*)hWh, N_NODES);
        k_aggr<<<(N_NODES + 3) / 4, 256, 0, stream>>>(rowptr, csr, hWh, inv,
                                                      convb + l * HDIM, gamma + l * HDIM,
                                                      beta + l * HDIM, mean + l * HDIM,
                                                      var + l * HDIM, h16);
    }

    // ---- pool + head (fused) ----
    k_pool_head1<<<G_GRAPHS / 64, 256, 0, stream>>>(h16, batch, Wt + WT_H1, b1, g1h);
    k_head23<<<G_GRAPHS / 64, 128, 0, stream>>>(g1h, Wt + WT_H2, b2, W3, b3, out);
}

// Round 12
// 597.814 us; speedup vs baseline: 1.1155x; 1.1155x over previous
//
#include <hip/hip_runtime.h>
#include <hip/hip_bf16.h>
#include <hip/hip_fp16.h>

#define N_NODES 50000
#define F_IN    64
#define HDIM    256
#define E_EDGES 800000
#define G_GRAPHS 2048
#define L_LAYERS 4
#define T_OUT   4
#define BN_EPS  1e-5f

#define NPAD    50176   // 196 * 256
#define NBLK    196
#define LDK     264     // fp16 LDS row stride for K=256 tiles

// Wt buffer offsets (fp16 elements)
#define WT_CONV 0
#define WT_PROJ 262144
#define WT_H1   278528
#define WT_H2   409600
#define WT_TOT  442368

typedef _Float16 half8 __attribute__((ext_vector_type(8)));
typedef float    f32x4 __attribute__((ext_vector_type(4)));

// ---- degree count + all weight transposes (fused, independent work) --------
__global__ void k_deg_wcvt(const int* __restrict__ dst, int* __restrict__ cnt,
                           const float* __restrict__ convW, const float* __restrict__ projW,
                           const float* __restrict__ W1, const float* __restrict__ W2,
                           _Float16* __restrict__ Wt) {
    int i = blockIdx.x * 256 + threadIdx.x;
    if (i < E_EDGES) atomicAdd(&cnt[dst[i]], 1);
    if (i < 262144) {                       // conv: 4 x [256x256]
        int l = i >> 16, r = i & 65535;
        int k = r >> 8, n = r & 255;
        Wt[WT_CONV + (size_t)l * 65536 + n * 256 + k] = (_Float16)convW[(size_t)l * 65536 + k * 256 + n];
        return;
    }
    int j = i - 262144;
    if (j >= 0 && j < 16384) {              // proj: [64x256] -> [256][64]
        int k = j >> 8, n = j & 255;
        Wt[WT_PROJ + n * 64 + k] = (_Float16)projW[k * 256 + n];
        return;
    }
    j -= 16384;
    if (j >= 0 && j < 131072) {             // W1: [512x256] -> [256][512]
        int k = j >> 8, n = j & 255;
        Wt[WT_H1 + n * 512 + k] = (_Float16)W1[k * 256 + n];
        return;
    }
    j -= 131072;
    if (j >= 0 && j < 32768) {              // W2: [256x128] -> [128][256]
        int k = j >> 7, n = j & 127;
        Wt[WT_H2 + n * 256 + k] = (_Float16)W2[k * 128 + n];
    }
}

// ---- scan pass 1: per-block inclusive scan ---------------------------------
__global__ void k_scan1(const int* __restrict__ cnt, int* __restrict__ iscan,
                        int* __restrict__ bsum) {
    __shared__ int sm[256];
    int t = threadIdx.x, i = blockIdx.x * 256 + t;
    sm[t] = cnt[i];
    __syncthreads();
    for (int off = 1; off < 256; off <<= 1) {
        int u = (t >= off) ? sm[t - off] : 0;
        __syncthreads();
        sm[t] += u;
        __syncthreads();
    }
    iscan[i] = sm[t];
    if (t == 255) bsum[blockIdx.x] = sm[255];
}

// ---- scan pass 2: block offset computed locally + emit rowptr/wpos/inv -----
__global__ void k_scan23(const int* __restrict__ cnt, const int* __restrict__ iscan,
                         const int* __restrict__ bsum, int* __restrict__ rowptr,
                         int* __restrict__ wpos, float* __restrict__ inv) {
    __shared__ int sm[256];
    int t = threadIdx.x;
    int b = blockIdx.x;
    sm[t] = (t < b) ? bsum[t] : 0;   // t < b <= 195 < NBLK
    __syncthreads();
    for (int off = 128; off > 0; off >>= 1) {
        if (t < off) sm[t] += sm[t + off];
        __syncthreads();
    }
    int boff = sm[0];
    int i = b * 256 + t;
    int c = cnt[i];
    int excl = boff + iscan[i] - c;
    rowptr[i] = excl;
    wpos[i] = excl;
    inv[i] = rsqrtf((float)c + 1.0f);
}

// ---- scatter edges into CSR order (src ids fit in ushort: N < 65536) -------
__global__ void k_scatter(const int* __restrict__ ei, int* __restrict__ wpos,
                          ushort* __restrict__ csr_src) {
    int e = blockIdx.x * blockDim.x + threadIdx.x;
    if (e < E_EDGES) {
        int s = ei[e];
        int d = ei[E_EDGES + e];
        int pos = atomicAdd(&wpos[d], 1);
        csr_src[pos] = (ushort)s;
    }
}

// ---- proj GEMM via MFMA: h16 = fp16(relu(x @ Wp + b)) ----------------------
__global__ __launch_bounds__(256) void k_proj_mfma(const float* __restrict__ x,
                                                   const _Float16* __restrict__ Wpt,
                                                   const float* __restrict__ bias,
                                                   ushort* __restrict__ h16, int nrows) {
    __shared__ _Float16 hs[64 * 72];
    int block_r = blockIdx.x * 64;
    for (int i = threadIdx.x; i < 64 * 16; i += 256) {
        int row = i >> 4;
        int c4 = (i & 15) * 4;
        float4 v = (block_r + row < nrows)
                       ? *(const float4*)(x + (size_t)(block_r + row) * F_IN + c4)
                       : make_float4(0.f, 0.f, 0.f, 0.f);
        _Float16* p = &hs[row * 72 + c4];
        p[0] = (_Float16)v.x; p[1] = (_Float16)v.y;
        p[2] = (_Float16)v.z; p[3] = (_Float16)v.w;
    }
    __syncthreads();

    int wave = threadIdx.x >> 6;
    int lane = threadIdx.x & 63;
    int l16 = lane & 15;
    int quad = lane >> 4;
    int n0 = wave * 64;

    f32x4 acc[4][4] = {};
#pragma unroll
    for (int k0 = 0; k0 < F_IN; k0 += 32) {
        half8 a[4], b[4];
#pragma unroll
        for (int ai = 0; ai < 4; ai++)
            a[ai] = *(const half8*)&hs[(ai * 16 + l16) * 72 + k0 + quad * 8];
#pragma unroll
        for (int bj = 0; bj < 4; bj++)
            b[bj] = *(const half8*)&Wpt[(size_t)(n0 + bj * 16 + l16) * F_IN + k0 + quad * 8];
#pragma unroll
        for (int ai = 0; ai < 4; ai++)
#pragma unroll
            for (int bj = 0; bj < 4; bj++)
                acc[ai][bj] = __builtin_amdgcn_mfma_f32_16x16x32_f16(a[ai], b[bj], acc[ai][bj], 0, 0, 0);
    }

#pragma unroll
    for (int ai = 0; ai < 4; ai++) {
        int rowb = block_r + ai * 16 + quad * 4;
#pragma unroll
        for (int r = 0; r < 4; r++) {
            int row = rowb + r;
            if (row >= nrows) continue;
#pragma unroll
            for (int bj = 0; bj < 4; bj++) {
                int col = n0 + bj * 16 + l16;
                float v = fmaxf(acc[ai][bj][r] + bias[col], 0.f);
                h16[(size_t)row * HDIM + col] = __half_as_ushort(__float2half(v));
            }
        }
    }
}

// ---- conv GEMM via MFMA: hWh = fp16((h16 @ W) * inv[row]) ------------------
__global__ __launch_bounds__(256) void k_gemm_mfma(const ushort* __restrict__ h16,
                                                   const _Float16* __restrict__ Wt,
                                                   const float* __restrict__ inv,
                                                   _Float16* __restrict__ outh, int nrows) {
    __shared__ _Float16 hs[64 * LDK];
    int block_r = blockIdx.x * 64;
    for (int i = threadIdx.x; i < 64 * 32; i += 256) {
        int row = i >> 5;
        int c16 = (i & 31) * 8;
        uint4 v;
        if (block_r + row < nrows)
            v = *(const uint4*)(h16 + (size_t)(block_r + row) * HDIM + c16);
        else
            v = make_uint4(0u, 0u, 0u, 0u);
        *(uint4*)&hs[row * LDK + c16] = v;
    }
    __syncthreads();

    int wave = threadIdx.x >> 6;
    int lane = threadIdx.x & 63;
    int l16 = lane & 15;
    int quad = lane >> 4;
    int n0 = wave * 64;

    f32x4 acc[4][4] = {};
    for (int k0 = 0; k0 < HDIM; k0 += 32) {
        half8 a[4], b[4];
#pragma unroll
        for (int ai = 0; ai < 4; ai++)
            a[ai] = *(const half8*)&hs[(ai * 16 + l16) * LDK + k0 + quad * 8];
#pragma unroll
        for (int bj = 0; bj < 4; bj++)
            b[bj] = *(const half8*)&Wt[(size_t)(n0 + bj * 16 + l16) * HDIM + k0 + quad * 8];
#pragma unroll
        for (int ai = 0; ai < 4; ai++)
#pragma unroll
            for (int bj = 0; bj < 4; bj++)
                acc[ai][bj] = __builtin_amdgcn_mfma_f32_16x16x32_f16(a[ai], b[bj], acc[ai][bj], 0, 0, 0);
    }

#pragma unroll
    for (int ai = 0; ai < 4; ai++) {
        int rowb = block_r + ai * 16 + quad * 4;
#pragma unroll
        for (int r = 0; r < 4; r++) {
            int row = rowb + r;
            if (row >= nrows) continue;
            float sc = inv[row];
#pragma unroll
            for (int bj = 0; bj < 4; bj++) {
                outh[(size_t)row * HDIM + n0 + bj * 16 + l16] = (_Float16)(acc[ai][bj][r] * sc);
            }
        }
    }
}

// ---- fused CSR aggregation + self-loop + bias + BN + relu + residual -------
__global__ __launch_bounds__(256) void k_aggr(const int* __restrict__ rowptr,
                                              const ushort* __restrict__ csr,
                                              const ushort* __restrict__ hWh,
                                              const float* __restrict__ inv,
                                              const float* __restrict__ cb,
                                              const float* __restrict__ gamma,
                                              const float* __restrict__ beta,
                                              const float* __restrict__ mean,
                                              const float* __restrict__ var,
                                              ushort* __restrict__ h16) {
    int node = blockIdx.x * 4 + (threadIdx.x >> 6);
    if (node >= N_NODES) return;
    int lane = threadIdx.x & 63;
    int g = lane >> 5;     // edge sub-slot (0/1)
    int f = lane & 31;     // 16B granule: features f*8 .. f*8+7
    const uint4* tbl = (const uint4*)hWh;   // row = 32 granules

    __half2 acc4[4];
#pragma unroll
    for (int i = 0; i < 4; i++) acc4[i] = __floats2half2_rn(0.f, 0.f);

    int beg = rowptr[node], end = rowptr[node + 1];
    for (int base = beg; base < end; base += 64) {
        int m = end - base; if (m > 64) m = 64;
        int myidx = (lane < m) ? (int)csr[base + lane] : 0;
        int jj = 0;
        for (; jj + 16 <= m; jj += 16) {
            int s0 = __shfl(myidx, jj + 0 + g);
            int s1 = __shfl(myidx, jj + 2 + g);
            int s2 = __shfl(myidx, jj + 4 + g);
            int s3 = __shfl(myidx, jj + 6 + g);
            int s4 = __shfl(myidx, jj + 8 + g);
            int s5 = __shfl(myidx, jj + 10 + g);
            int s6 = __shfl(myidx, jj + 12 + g);
            int s7 = __shfl(myidx, jj + 14 + g);
            uint4 u0 = tbl[(size_t)s0 * 32 + f];
            uint4 u1 = tbl[(size_t)s1 * 32 + f];
            uint4 u2 = tbl[(size_t)s2 * 32 + f];
            uint4 u3 = tbl[(size_t)s3 * 32 + f];
            uint4 u4 = tbl[(size_t)s4 * 32 + f];
            uint4 u5 = tbl[(size_t)s5 * 32 + f];
            uint4 u6 = tbl[(size_t)s6 * 32 + f];
            uint4 u7 = tbl[(size_t)s7 * 32 + f];
            const __half2* p0 = (const __half2*)&u0;
            const __half2* p1 = (const __half2*)&u1;
            const __half2* p2 = (const __half2*)&u2;
            const __half2* p3 = (const __half2*)&u3;
            const __half2* p4 = (const __half2*)&u4;
            const __half2* p5 = (const __half2*)&u5;
            const __half2* p6 = (const __half2*)&u6;
            const __half2* p7 = (const __half2*)&u7;
#pragma unroll
            for (int i = 0; i < 4; i++) {
                __half2 a = __hadd2(__hadd2(p0[i], p1[i]), __hadd2(p2[i], p3[i]));
                __half2 b = __hadd2(__hadd2(p4[i], p5[i]), __hadd2(p6[i], p7[i]));
                acc4[i] = __hadd2(acc4[i], __hadd2(a, b));
            }
        }
        if (jj + 8 <= m) {
            int s0 = __shfl(myidx, jj + 0 + g);
            int s1 = __shfl(myidx, jj + 2 + g);
            int s2 = __shfl(myidx, jj + 4 + g);
            int s3 = __shfl(myidx, jj + 6 + g);
            uint4 u0 = tbl[(size_t)s0 * 32 + f];
            uint4 u1 = tbl[(size_t)s1 * 32 + f];
            uint4 u2 = tbl[(size_t)s2 * 32 + f];
            uint4 u3 = tbl[(size_t)s3 * 32 + f];
            const __half2* p0 = (const __half2*)&u0;
            const __half2* p1 = (const __half2*)&u1;
            const __half2* p2 = (const __half2*)&u2;
            const __half2* p3 = (const __half2*)&u3;
#pragma unroll
            for (int i = 0; i < 4; i++)
                acc4[i] = __hadd2(acc4[i], __hadd2(__hadd2(p0[i], p1[i]), __hadd2(p2[i], p3[i])));
            jj += 8;
        }
        for (; jj < m; jj += 2) {
            int e = jj + g;
            int s = __shfl(myidx, (e < m) ? e : (m - 1));
            uint4 u = tbl[(size_t)s * 32 + f];
            if (e < m) {
                const __half2* p = (const __half2*)&u;
#pragma unroll
                for (int i = 0; i < 4; i++) acc4[i] = __hadd2(acc4[i], p[i]);
            }
        }
    }

#pragma unroll
    for (int i = 0; i < 4; i++) {
        unsigned int packed = *(unsigned int*)&acc4[i];
        unsigned int other = __shfl_xor((int)packed, 32);
        acc4[i] = __hadd2(acc4[i], *(__half2*)&other);
    }

    if (g == 0) {
        float acc[8];
#pragma unroll
        for (int i = 0; i < 4; i++) {
            float2 t = __half22float2(acc4[i]);
            acc[2 * i] = t.x; acc[2 * i + 1] = t.y;
        }
        uint4 us = tbl[(size_t)node * 32 + f];
        const __half2* ps = (const __half2*)&us;
#pragma unroll
        for (int i = 0; i < 4; i++) {
            float2 t = __half22float2(ps[i]);
            acc[2 * i] += t.x;
            acc[2 * i + 1] += t.y;
        }
        int c0 = f * 8;
        float iv = inv[node];
        uint4 ur = *(const uint4*)(h16 + (size_t)node * HDIM + c0);
        const __half2* pr = (const __half2*)&ur;
        float resv[8];
#pragma unroll
        for (int i = 0; i < 4; i++) {
            float2 rr = __half22float2(pr[i]);
            resv[2 * i] = rr.x; resv[2 * i + 1] = rr.y;
        }
        float r8[8];
#pragma unroll
        for (int half = 0; half < 2; half++) {
            int c = c0 + half * 4;
            float4 bb = *(const float4*)(cb + c);
            float4 gm = *(const float4*)(gamma + c);
            float4 bt = *(const float4*)(beta + c);
            float4 mn = *(const float4*)(mean + c);
            float4 vr = *(const float4*)(var + c);
            float* a = &acc[half * 4];
            float* rs = &resv[half * 4];
            r8[half * 4 + 0] = fmaxf((a[0] * iv + bb.x - mn.x) * rsqrtf(vr.x + BN_EPS) * gm.x + bt.x, 0.f) + rs[0];
            r8[half * 4 + 1] = fmaxf((a[1] * iv + bb.y - mn.y) * rsqrtf(vr.y + BN_EPS) * gm.y + bt.y, 0.f) + rs[1];
            r8[half * 4 + 2] = fmaxf((a[2] * iv + bb.z - mn.z) * rsqrtf(vr.z + BN_EPS) * gm.z + bt.z, 0.f) + rs[2];
            r8[half * 4 + 3] = fmaxf((a[3] * iv + bb.w - mn.w) * rsqrtf(vr.w + BN_EPS) * gm.w + bt.w, 0.f) + rs[3];
        }
        __half2 q0 = __floats2half2_rn(r8[0], r8[1]);
        __half2 q1 = __floats2half2_rn(r8[2], r8[3]);
        __half2 q2 = __floats2half2_rn(r8[4], r8[5]);
        __half2 q3 = __floats2half2_rn(r8[6], r8[7]);
        uint4 uo;
        uo.x = *(unsigned int*)&q0; uo.y = *(unsigned int*)&q1;
        uo.z = *(unsigned int*)&q2; uo.w = *(unsigned int*)&q3;
        *(uint4*)(h16 + (size_t)node * HDIM + c0) = uo;
    }
}

// ---- pooling: one block per graph, fp16 in/out -----------------------------
__global__ void k_pool(const ushort* __restrict__ h16, const int* __restrict__ batch,
                       ushort* __restrict__ gp16) {
    int g = blockIdx.x;
    __shared__ int s_lo, s_hi;
    if (threadIdx.x == 0) {
        int lo = 0, hi = N_NODES;
        while (lo < hi) { int m = (lo + hi) >> 1; if (batch[m] < g) lo = m + 1; else hi = m; }
        s_lo = lo;
        hi = N_NODES;
        while (lo < hi) { int m = (lo + hi) >> 1; if (batch[m] < g + 1) lo = m + 1; else hi = m; }
        s_hi = lo;
    }
    __syncthreads();
    int lo = s_lo, hi = s_hi;
    int t = threadIdx.x;
    float sum = 0.0f, mx = -1e30f;
    for (int n = lo; n < hi; n++) {
        float v = __half2float(__ushort_as_half(h16[(size_t)n * HDIM + t]));
        sum += v;
        mx = fmaxf(mx, v);
    }
    float cntf = fmaxf((float)(hi - lo), 1.0f);
    float mean = sum / cntf;
    float mxo = (hi > lo) ? mx : 0.0f;
    gp16[(size_t)g * 2 * HDIM + t] = __half_as_ushort(__float2half(mean));
    gp16[(size_t)g * 2 * HDIM + HDIM + t] = __half_as_ushort(__float2half(mxo));
}

// ---- head1 via MFMA: g1h = fp16(relu(gp16 @ W1 + b1)) ----------------------
__global__ __launch_bounds__(256) void k_head1_mfma(const ushort* __restrict__ A,
                                                    const _Float16* __restrict__ Bt,
                                                    const float* __restrict__ bias,
                                                    ushort* __restrict__ out16) {
    constexpr int K = 512, LDKH = 520;
    __shared__ _Float16 hs[64 * LDKH];
    int block_r = blockIdx.x * 64;
    for (int i = threadIdx.x; i < 64 * (K / 8); i += 256) {
        int row = i / (K / 8);
        int c = (i % (K / 8)) * 8;
        *(uint4*)&hs[row * LDKH + c] = *(const uint4*)(A + (size_t)(block_r + row) * K + c);
    }
    __syncthreads();

    int wave = threadIdx.x >> 6;
    int lane = threadIdx.x & 63;
    int l16 = lane & 15;
    int quad = lane >> 4;
    int n0 = wave * 64;

    f32x4 acc[4][4] = {};
    for (int k0 = 0; k0 < K; k0 += 32) {
        half8 a[4], b[4];
#pragma unroll
        for (int ai = 0; ai < 4; ai++)
            a[ai] = *(const half8*)&hs[(ai * 16 + l16) * LDKH + k0 + quad * 8];
#pragma unroll
        for (int bj = 0; bj < 4; bj++)
            b[bj] = *(const half8*)&Bt[(size_t)(n0 + bj * 16 + l16) * K + k0 + quad * 8];
#pragma unroll
        for (int ai = 0; ai < 4; ai++)
#pragma unroll
            for (int bj = 0; bj < 4; bj++)
                acc[ai][bj] = __builtin_amdgcn_mfma_f32_16x16x32_f16(a[ai], b[bj], acc[ai][bj], 0, 0, 0);
    }

#pragma unroll
    for (int ai = 0; ai < 4; ai++) {
        int rowb = block_r + ai * 16 + quad * 4;
#pragma unroll
        for (int r = 0; r < 4; r++) {
            int row = rowb + r;
#pragma unroll
            for (int bj = 0; bj < 4; bj++) {
                int col = n0 + bj * 16 + l16;
                float v = fmaxf(acc[ai][bj][r] + bias[col], 0.f);
                out16[(size_t)row * HDIM + col] = __half_as_ushort(__float2half(v));
            }
        }
    }
}

// ---- fused head2 + head3: block = 64 graphs, 128 threads -------------------
__global__ __launch_bounds__(128) void k_head23(const ushort* __restrict__ g1h,
                                                const _Float16* __restrict__ W2t,
                                                const float* __restrict__ b2,
                                                const float* __restrict__ W3,
                                                const float* __restrict__ b3,
                                                float* __restrict__ out) {
    __shared__ _Float16 hs[64 * 264];
    __shared__ float g2s[64 * 132];
    int block_r = blockIdx.x * 64;
    for (int i = threadIdx.x; i < 64 * 32; i += 128) {
        int row = i >> 5;
        int c = (i & 31) * 8;
        *(uint4*)&hs[row * 264 + c] = *(const uint4*)(g1h + (size_t)(block_r + row) * HDIM + c);
    }
    __syncthreads();

    int wave = threadIdx.x >> 6;
    int lane = threadIdx.x & 63;
    int l16 = lane & 15;
    int quad = lane >> 4;
    int n0 = wave * 64;

    f32x4 acc[4][4] = {};
    for (int k0 = 0; k0 < HDIM; k0 += 32) {
        half8 a[4], b[4];
#pragma unroll
        for (int ai = 0; ai < 4; ai++)
            a[ai] = *(const half8*)&hs[(ai * 16 + l16) * 264 + k0 + quad * 8];
#pragma unroll
        for (int bj = 0; bj < 4; bj++)
            b[bj] = *(const half8*)&W2t[(size_t)(n0 + bj * 16 + l16) * HDIM + k0 + quad * 8];
#pragma unroll
        for (int ai = 0; ai < 4; ai++)
#pragma unroll
            for (int bj = 0; bj < 4; bj++)
                acc[ai][bj] = __builtin_amdgcn_mfma_f32_16x16x32_f16(a[ai], b[bj], acc[ai][bj], 0, 0, 0);
    }
#pragma unroll
    for (int ai = 0; ai < 4; ai++) {
        int rowb = ai * 16 + quad * 4;
#pragma unroll
        for (int r = 0; r < 4; r++) {
            int row = rowb + r;
#pragma unroll
            for (int bj = 0; bj < 4; bj++) {
                int col = n0 + bj * 16 + l16;
                g2s[row * 132 + col] = fmaxf(acc[ai][bj][r] + b2[col], 0.f);
            }
        }
    }
    __syncthreads();

    // head3: 64 rows x 4 cols; thread -> (row, col pair)
    int r = threadIdx.x >> 1;
    int p = threadIdx.x & 1;
    float a0 = b3[2 * p], a1 = b3[2 * p + 1];
    for (int k = 0; k < 128; k++) {
        float v = g2s[r * 132 + k];
        a0 += v * W3[k * T_OUT + 2 * p];
        a1 += v * W3[k * T_OUT + 2 * p + 1];
    }
    out[(size_t)(block_r + r) * T_OUT + 2 * p] = a0;
    out[(size_t)(block_r + r) * T_OUT + 2 * p + 1] = a1;
}

extern "C" void kernel_launch(void* const* d_in, const int* in_sizes, int n_in,
                              void* d_out, int out_size, void* d_ws, size_t ws_size,
                              hipStream_t stream) {
    const float* x     = (const float*)d_in[0];
    const int*   ei    = (const int*)d_in[1];
    const int*   batch = (const int*)d_in[2];
    const float* projW = (const float*)d_in[3];
    const float* projb = (const float*)d_in[4];
    const float* convW = (const float*)d_in[5];
    const float* convb = (const float*)d_in[6];
    const float* gamma = (const float*)d_in[7];
    const float* beta  = (const float*)d_in[8];
    const float* mean  = (const float*)d_in[9];
    const float* var   = (const float*)d_in[10];
    const float* W1    = (const float*)d_in[11];
    const float* b1    = (const float*)d_in[12];
    const float* W2    = (const float*)d_in[13];
    const float* b2    = (const float*)d_in[14];
    const float* W3    = (const float*)d_in[15];
    const float* b3    = (const float*)d_in[16];
    float* out = (float*)d_out;

    // workspace layout (all segments 16B aligned)
    float*  wsf    = (float*)d_ws;
    float*  inv    = wsf;                        // NPAD f
    int*    cnt    = (int*)(wsf + NPAD);         // NPAD i
    int*    rowptr = cnt + NPAD;                 // NPAD i
    int*    wpos   = rowptr + NPAD;              // NPAD i
    int*    iscan  = wpos + NPAD;                // NPAD i
    int*    bsum   = iscan + NPAD;               // 256 i
    int*    boff   = bsum + 256;                 // 256 i (unused, kept for layout)
    ushort* csr    = (ushort*)(boff + 256);      // 800256 u16
    ushort* hWh    = csr + 800256;               // N*H fp16 (messages)
    ushort* h16    = hWh + (size_t)N_NODES * HDIM;            // N*H fp16 residual stream
    ushort* gp16   = h16 + (size_t)N_NODES * HDIM;            // G*512 fp16
    ushort* g1h    = gp16 + (size_t)G_GRAPHS * 512;           // G*256 fp16
    _Float16* Wt   = (_Float16*)(g1h + (size_t)G_GRAPHS * HDIM); // WT_TOT fp16

    // ---- CSR build + weight transposes ----
    hipMemsetAsync(cnt, 0, NPAD * sizeof(int), stream);
    k_deg_wcvt<<<(E_EDGES + 255) / 256, 256, 0, stream>>>(ei + E_EDGES, cnt,
                                                          convW, projW, W1, W2, Wt);
    k_scan1<<<NBLK, 256, 0, stream>>>(cnt, iscan, bsum);
    k_scan23<<<NBLK, 256, 0, stream>>>(cnt, iscan, bsum, rowptr, wpos, inv);
    k_scatter<<<(E_EDGES + 255) / 256, 256, 0, stream>>>(ei, wpos, csr);

    // ---- proj (MFMA) ----
    int gemm_blocks = (N_NODES + 63) / 64;
    k_proj_mfma<<<gemm_blocks, 256, 0, stream>>>(x, Wt + WT_PROJ, projb, h16, N_NODES);

    // ---- GCN layers ----
    for (int l = 0; l < L_LAYERS; l++) {
        k_gemm_mfma<<<gemm_blocks, 256, 0, stream>>>(h16, Wt + WT_CONV + (size_t)l * HDIM * HDIM,
                                                     inv, (_Float16*)hWh, N_NODES);
        k_aggr<<<(N_NODES + 3) / 4, 256, 0, stream>>>(rowptr, csr, hWh, inv,
                                                      convb + l * HDIM, gamma + l * HDIM,
                                                      beta + l * HDIM, mean + l * HDIM,
                                                      var + l * HDIM, h16);
    }

    // ---- pool + head ----
    k_pool<<<G_GRAPHS, HDIM, 0, stream>>>(h16, batch, gp16);
    k_head1_mfma<<<G_GRAPHS / 64, 256, 0, stream>>>(gp16, Wt + WT_H1, b1, g1h);
    k_head23<<<G_GRAPHS / 64, 128, 0, stream>>>(g1h, Wt + WT_H2, b2, W3, b3, out);
}